// Round 1
// baseline (746.354 us; speedup 1.0000x reference)
//
#include <hip/hip_runtime.h>

// NCEAverage: scores[b,k] = exp(dot(memory[idx'[b,k]], x[b]) / T); out = scores / Z
// where idx'[:,0] = y, Z = mean(scores) * N.
// B=256, K=4096, D=128, N=1e6, T=0.07. Memory-bound: ~512 MB of gathered rows.

constexpr int Bc = 256;
constexpr int Kc = 4096;
constexpr int Dc = 128;
constexpr long long Nc = 1000000;
constexpr int KPB = 64;          // k's per block; grid = (K/KPB, B)

// Phase 1: one 32-lane group computes one (b,k) dot+exp.
// Lane l loads memory[row][4l..4l+3] as float4 -> 32 lanes cover the whole
// 512 B row in one coalesced dwordx4 instruction per half-wave.
__global__ __launch_bounds__(256) void nce_scores(
    const float* __restrict__ x, const int* __restrict__ y,
    const int* __restrict__ idxp, const float* __restrict__ memory,
    float* __restrict__ out, double* __restrict__ partial)
{
    __shared__ float xs[Dc];
    __shared__ double bsum[8];
    const int b   = blockIdx.y;
    const int tid = threadIdx.x;

    // stage x[b] (512 B) in LDS
    if (tid < Dc / 4)
        ((float4*)xs)[tid] = ((const float4*)(x + (long)b * Dc))[tid];
    __syncthreads();

    const int group = tid >> 5;   // 0..7 (8 groups of 32 lanes)
    const int lane  = tid & 31;
    const float4 xf = ((const float4*)xs)[lane];

    const int   kbase = blockIdx.x * KPB;
    const float invT  = 1.0f / 0.07f;
    double local = 0.0;

#pragma unroll
    for (int it = 0; it < KPB / 8; ++it) {
        const int kk  = kbase + it * 8 + group;
        // column 0 of idx is forced to the positive index y[b]
        const int ind = (kk == 0) ? y[b] : idxp[(long)b * Kc + kk];
        const float4 w = ((const float4*)(memory + (long)ind * Dc))[lane];
        float dot = w.x * xf.x + w.y * xf.y + w.z * xf.z + w.w * xf.w;
        // butterfly reduce over the 32-lane group (masks <32 stay in-group on wave64)
#pragma unroll
        for (int m = 16; m >= 1; m >>= 1)
            dot += __shfl_xor(dot, m, 64);
        const float score = expf(dot * invT);
        if (lane == 0) {
            out[(long)b * Kc + kk] = score;
            local += (double)score;
        }
    }

    if (lane == 0) bsum[group] = local;
    __syncthreads();
    if (tid == 0) {
        double s = 0.0;
#pragma unroll
        for (int g = 0; g < 8; ++g) s += bsum[g];
        // spread contention over 8 cells (one per XCD-ish); 16384 atomics total
        unsafeAtomicAdd(&partial[blockIdx.x & 7], s);
    }
}

// Phase 2: out *= (B*K) / (N * sum)
__global__ __launch_bounds__(256) void nce_norm(
    float* __restrict__ out, const double* __restrict__ partial)
{
    double s = 0.0;
#pragma unroll
    for (int g = 0; g < 8; ++g) s += partial[g];
    const float scale = (float)((double)((long long)Bc * Kc) / ((double)Nc * s));
    const int i = blockIdx.x * blockDim.x + threadIdx.x;
    float4 v = ((float4*)out)[i];
    v.x *= scale; v.y *= scale; v.z *= scale; v.w *= scale;
    ((float4*)out)[i] = v;
}

extern "C" void kernel_launch(void* const* d_in, const int* in_sizes, int n_in,
                              void* d_out, int out_size, void* d_ws, size_t ws_size,
                              hipStream_t stream) {
    const float* x      = (const float*)d_in[0];
    const int*   y      = (const int*)  d_in[1];
    const int*   idx    = (const int*)  d_in[2];
    const float* memory = (const float*)d_in[3];
    float*  out     = (float*)d_out;
    double* partial = (double*)d_ws;

    hipMemsetAsync(partial, 0, 8 * sizeof(double), stream);

    dim3 g1(Kc / KPB, Bc);
    nce_scores<<<g1, 256, 0, stream>>>(x, y, idx, memory, out, partial);

    const int n4 = Bc * Kc / 4;                  // 262144 float4 elements
    nce_norm<<<n4 / 256, 256, 0, stream>>>(out, partial);
}